// Round 1
// baseline (26.353 us; speedup 1.0000x reference)
//
#include <hip/hip_runtime.h>
#include <math.h>

#define NWAVE 64
#define DMODEL 128
#define BLOCK 256

// One block per (b, i) query row.
// Phase 1: all 256 threads compute r_ij / masked 1/r for j = 0..N-1 into LDS.
// Phase 2: lane (tid&63) = wavelength w, wave (tid>>6) = j-chunk; accumulate
//          sum_j cos/sin(k_w * r_ij) / r_ij. LDS-reduce 4 chunks, store.
__global__ __launch_bounds__(BLOCK) void spatial_embed_kernel(
    const float* __restrict__ x,            // [B, N, 3]
    const unsigned char* __restrict__ mask, // [B, N] (bool; 0 = valid)
    float* __restrict__ out,                // [B, N, DMODEL]
    int B, int N)
{
    const int bi = blockIdx.x;           // b*N + i
    const int b  = bi / N;
    const int i  = bi - b * N;
    const int tid = threadIdx.x;

    __shared__ float2 r_inv[768];        // {r, masked 1/r}
    __shared__ float2 partial[BLOCK];

    // query point (broadcast loads)
    const float xi = x[bi * 3 + 0];
    const float yi = x[bi * 3 + 1];
    const float zi = x[bi * 3 + 2];

    // ---- phase 1: distances into LDS ----
    for (int j = tid; j < N; j += BLOCK) {
        const float dx = xi - x[(b * N + j) * 3 + 0];
        const float dy = yi - x[(b * N + j) * 3 + 1];
        const float dz = zi - x[(b * N + j) * 3 + 2];
        const float r  = sqrtf(fmaf(dx, dx, fmaf(dy, dy, fmaf(dz, dz, 1e-6f))));
        const bool valid = (j != i) && (mask[b * N + j] == 0);
        r_inv[j] = make_float2(r, valid ? (1.0f / r) : 0.0f);
    }
    __syncthreads();

    // ---- phase 2: superpose over j ----
    const int w     = tid & (NWAVE - 1);
    const int chunk = tid >> 6;          // 0..3 (wave index)

    // lambda_w = geomspace(2, 50, 64)[w] = 2 * 25^(w/63); k = 2*pi/lambda (fp32, as ref)
    const double lam = 2.0 * pow(25.0, (double)w / 63.0);
    const float  kw  = (float)(6.283185307179586 / lam);

    float accR = 0.0f, accI = 0.0f;
    const int jspan = N / 4;
    const int j0 = chunk * jspan;
    #pragma unroll 4
    for (int j = j0; j < j0 + jspan; ++j) {
        const float2 ri = r_inv[j];      // wave-uniform address -> broadcast
        const float phase = ri.x * kw;
        float s, c;
        __sincosf(phase, &s, &c);
        accR = fmaf(c, ri.y, accR);
        accI = fmaf(s, ri.y, accI);
    }

    partial[tid] = make_float2(accR, accI);
    __syncthreads();

    // ---- reduce 4 chunks, store interleaved (re, im) ----
    if (tid < NWAVE) {
        const float2 p0 = partial[tid];
        const float2 p1 = partial[tid + 64];
        const float2 p2 = partial[tid + 128];
        const float2 p3 = partial[tid + 192];
        float re = (p0.x + p1.x) + (p2.x + p3.x);
        float im = (p0.y + p1.y) + (p2.y + p3.y);
        const bool maskedQ = (mask[bi] != 0);
        if (maskedQ) { re = 0.0f; im = 0.0f; }
        out[bi * DMODEL + 2 * tid + 0] = re;
        out[bi * DMODEL + 2 * tid + 1] = im;
    }
}

extern "C" void kernel_launch(void* const* d_in, const int* in_sizes, int n_in,
                              void* d_out, int out_size, void* d_ws, size_t ws_size,
                              hipStream_t stream) {
    const float* x = (const float*)d_in[0];
    const unsigned char* mask = (const unsigned char*)d_in[1];
    float* out = (float*)d_out;

    const int N = 768;                       // fixed by setup_inputs
    const int BN = in_sizes[1];              // B*N
    const int B = BN / N;

    spatial_embed_kernel<<<dim3(BN), dim3(BLOCK), 0, stream>>>(x, mask, out, B, N);
}

// Round 2
// 25.512 us; speedup vs baseline: 1.0330x; 1.0330x over previous
//
#include <hip/hip_runtime.h>
#include <math.h>

#define NWAVE 64
#define DMODEL 128
#define BLOCK 256
#define N_FIXED 768
#define NSPLIT 2
#define JSPAN (N_FIXED / NSPLIT)   // 384 j's per block

// grid = B*N*NSPLIT blocks; block (bi, split) accumulates the partial
// superposition over its j-chunk for query row bi, then atomicAdds into out.
// Exactly NSPLIT=2 addends per output word (float add commutative -> bit-stable).
__global__ __launch_bounds__(BLOCK) void spatial_embed_kernel(
    const float* __restrict__ x,            // [B, N, 3]
    const unsigned char* __restrict__ mask, // [B, N] bool (0 = valid)
    float* __restrict__ out,                // [B, N, DMODEL], pre-zeroed
    int B, int N)
{
    const int blk   = blockIdx.x;
    const int split = blk % NSPLIT;
    const int bi    = blk / NSPLIT;          // b*N + i
    const int b     = bi / N;
    const int i     = bi - b * N;
    const int tid   = threadIdx.x;

    __shared__ __align__(16) float s_r[JSPAN];
    __shared__ __align__(16) float s_invr[JSPAN];
    __shared__ float2 partial[BLOCK];

    const int jbase = split * JSPAN;

    const float xi = x[bi * 3 + 0];
    const float yi = x[bi * 3 + 1];
    const float zi = x[bi * 3 + 2];

    // ---- phase 1: distances for this block's j-chunk into LDS (SoA) ----
    for (int jj = tid; jj < JSPAN; jj += BLOCK) {
        const int j = jbase + jj;
        const float dx = xi - x[(b * N + j) * 3 + 0];
        const float dy = yi - x[(b * N + j) * 3 + 1];
        const float dz = zi - x[(b * N + j) * 3 + 2];
        const float r  = sqrtf(fmaf(dx, dx, fmaf(dy, dy, fmaf(dz, dz, 1e-6f))));
        const bool valid = (j != i) && (mask[b * N + j] == 0);
        s_r[jj]    = r;
        s_invr[jj] = valid ? (1.0f / r) : 0.0f;
    }
    __syncthreads();

    // ---- phase 2: lane = wavelength, wave = j-subchunk ----
    const int w     = tid & (NWAVE - 1);
    const int chunk = tid >> 6;              // 0..3

    // rev = r / lambda_w  (v_sin/v_cos take revolutions: sin(2*pi*rev) = sin(k_w*r))
    // 1/lambda_w = 0.5 * 25^(-w/63) = 0.5 * exp2(-w * log2(25)/63)
    const float invlam = 0.5f * exp2f((float)w * (-4.643856189774724f / 63.0f));

    float accR = 0.0f, accI = 0.0f;
    const int nq = JSPAN / 4 / 4;            // 24 float4 quads per chunk
    const int q0 = chunk * nq;
    const float4* r4 = (const float4*)s_r;
    const float4* v4 = (const float4*)s_invr;

    #pragma unroll 2
    for (int q = q0; q < q0 + nq; ++q) {
        const float4 rr = r4[q];             // ds_read_b128, wave-uniform broadcast
        const float4 vv = v4[q];

        float s0 = __builtin_amdgcn_sinf(rr.x * invlam);
        float c0 = __builtin_amdgcn_cosf(rr.x * invlam);
        accR = fmaf(c0, vv.x, accR);  accI = fmaf(s0, vv.x, accI);

        float s1 = __builtin_amdgcn_sinf(rr.y * invlam);
        float c1 = __builtin_amdgcn_cosf(rr.y * invlam);
        accR = fmaf(c1, vv.y, accR);  accI = fmaf(s1, vv.y, accI);

        float s2 = __builtin_amdgcn_sinf(rr.z * invlam);
        float c2 = __builtin_amdgcn_cosf(rr.z * invlam);
        accR = fmaf(c2, vv.z, accR);  accI = fmaf(s2, vv.z, accI);

        float s3 = __builtin_amdgcn_sinf(rr.w * invlam);
        float c3 = __builtin_amdgcn_cosf(rr.w * invlam);
        accR = fmaf(c3, vv.w, accR);  accI = fmaf(s3, vv.w, accI);
    }

    partial[tid] = make_float2(accR, accI);
    __syncthreads();

    // ---- reduce 4 chunks, atomicAdd into out ----
    if (tid < NWAVE) {
        const float2 p0 = partial[tid];
        const float2 p1 = partial[tid + 64];
        const float2 p2 = partial[tid + 128];
        const float2 p3 = partial[tid + 192];
        const float re = (p0.x + p1.x) + (p2.x + p3.x);
        const float im = (p0.y + p1.y) + (p2.y + p3.y);
        if (mask[bi] == 0) {                 // masked query rows stay zero
            atomicAdd(&out[bi * DMODEL + 2 * tid + 0], re);
            atomicAdd(&out[bi * DMODEL + 2 * tid + 1], im);
        }
    }
}

extern "C" void kernel_launch(void* const* d_in, const int* in_sizes, int n_in,
                              void* d_out, int out_size, void* d_ws, size_t ws_size,
                              hipStream_t stream) {
    const float* x = (const float*)d_in[0];
    const unsigned char* mask = (const unsigned char*)d_in[1];
    float* out = (float*)d_out;

    const int N = N_FIXED;
    const int BN = in_sizes[1];              // B*N
    const int B = BN / N;

    hipMemsetAsync(d_out, 0, (size_t)out_size * sizeof(float), stream);
    spatial_embed_kernel<<<dim3(BN * NSPLIT), dim3(BLOCK), 0, stream>>>(x, mask, out, B, N);
}